// Round 1
// baseline (435.817 us; speedup 1.0000x reference)
//
#include <hip/hip_runtime.h>
#include <cstdint>
#include <cstddef>

#define N_NODES 50000
#define N_EDGES 640000
#define DF 128

// ---------------- setup: transpose weights to k-major + zero cursor ----------
// Wp_t[k*128+o]  = W_pool[o*128+k]
// Wn1_t[k*128+o] = W_neigh[o*256+k]        (first 128 cols -> multiplies feat)
// Wn2_t[k*128+o] = W_neigh[o*256+128+k]    (last 128 cols  -> multiplies neigh)
__global__ void setup_kernel(const float* __restrict__ W_pool,
                             const float* __restrict__ W_neigh,
                             float* __restrict__ Wp_t,
                             float* __restrict__ Wn1_t,
                             float* __restrict__ Wn2_t,
                             int* __restrict__ cursor) {
    int idx = blockIdx.x * blockDim.x + threadIdx.x;
    const int TT = 3 * 128 * 128;
    if (idx < TT) {
        int m = idx >> 14;       // which matrix
        int r = idx & 16383;
        int k = r >> 7, o = r & 127;
        if (m == 0)      Wp_t[r]  = W_pool[o * 128 + k];
        else if (m == 1) Wn1_t[r] = W_neigh[o * 256 + k];
        else             Wn2_t[r] = W_neigh[o * 256 + 128 + k];
    } else {
        int i = idx - TT;
        if (i < N_NODES) cursor[i] = 0;
    }
}

// ---------------- tiled fp32 GEMM: out[n][o] = bias[o] + sum_p A_p[n][:] @ Wt_p
// Wt is k-major: Wt[k*128 + o]. 32 rows/block, 256 threads, 4x4 micro-tile.
// LDS: W half-tile (64 k-rows, 32 KB) + A tile (32x128, 16 KB) = 48 KB.
// NOTE: A1 may alias out (neigh lives in d_out): each block stages its own
// 32 A-rows into LDS before storing those same 32 rows -> no hazard.
__global__ __launch_bounds__(256) void gemm_fused(
    const float* __restrict__ A0, const float* __restrict__ Wt0,
    const float* A1, const float* Wt1,
    const float* __restrict__ bias, float* out, int nphase)
{
    __shared__ float Wl[64 * 128];   // k-half-major
    __shared__ float Al[32 * 128];   // row-major
    const int t = threadIdx.x;
    const int colg = t & 31;         // float4 column group: cols 4*colg..+3
    const int rowg = t >> 5;         // 0..7 -> rows rowg*4..+3
    const int r0 = blockIdx.x * 32;

    float4 acc[4];
    {
        float4 bv = ((const float4*)bias)[colg];
        #pragma unroll
        for (int ri = 0; ri < 4; ++ri) acc[ri] = bv;
    }

    for (int p = 0; p < nphase; ++p) {
        const float* A  = p ? A1  : A0;
        const float* Wt = p ? Wt1 : Wt0;

        // stage A tile: 32 rows x 128 cols = 1024 float4, 4 per thread
        {
            const float4* A4 = (const float4*)A;
            float4* Al4 = (float4*)Al;
            #pragma unroll
            for (int i = 0; i < 4; ++i) {
                int idx = i * 256 + t;
                int row = idx >> 5, c4 = idx & 31;
                float4 v = make_float4(0.f, 0.f, 0.f, 0.f);
                if (r0 + row < N_NODES) v = A4[(size_t)(r0 + row) * 32 + c4];
                Al4[idx] = v;
            }
        }

        #pragma unroll
        for (int h = 0; h < 2; ++h) {            // two 64-k halves of W
            __syncthreads();
            // stage W half: 64 k-rows x 128 = 2048 float4, 8 per thread
            {
                const float4* Wt4 = (const float4*)(Wt + h * 64 * 128);
                float4* Wl4 = (float4*)Wl;
                #pragma unroll
                for (int i = 0; i < 8; ++i)
                    Wl4[i * 256 + t] = Wt4[i * 256 + t];
            }
            __syncthreads();

            for (int k = 0; k < 64; k += 4) {
                float4 b[4], a[4];
                #pragma unroll
                for (int j = 0; j < 4; ++j)
                    b[j] = ((const float4*)Wl)[(k + j) * 32 + colg];
                #pragma unroll
                for (int ri = 0; ri < 4; ++ri)
                    a[ri] = ((const float4*)Al)[(rowg * 4 + ri) * 32 + ((h * 64 + k) >> 2)];
                #pragma unroll
                for (int ri = 0; ri < 4; ++ri) {
                    float4 av = a[ri];
                    acc[ri].x = fmaf(av.x, b[0].x, fmaf(av.y, b[1].x, fmaf(av.z, b[2].x, fmaf(av.w, b[3].x, acc[ri].x))));
                    acc[ri].y = fmaf(av.x, b[0].y, fmaf(av.y, b[1].y, fmaf(av.z, b[2].y, fmaf(av.w, b[3].y, acc[ri].y))));
                    acc[ri].z = fmaf(av.x, b[0].z, fmaf(av.y, b[1].z, fmaf(av.z, b[2].z, fmaf(av.w, b[3].z, acc[ri].z))));
                    acc[ri].w = fmaf(av.x, b[0].w, fmaf(av.y, b[1].w, fmaf(av.z, b[2].w, fmaf(av.w, b[3].w, acc[ri].w))));
                }
            }
        }
        __syncthreads();   // before next phase restages Al
    }

    #pragma unroll
    for (int ri = 0; ri < 4; ++ri) {
        int row = r0 + rowg * 4 + ri;
        if (row < N_NODES) ((float4*)out)[(size_t)row * 32 + colg] = acc[ri];
    }
}

// ---------------- degree histogram ----------------
__global__ void hist_kernel(const int* __restrict__ dst, int* __restrict__ cursor) {
    int e = blockIdx.x * blockDim.x + threadIdx.x;
    if (e < N_EDGES) atomicAdd(&cursor[dst[e]], 1);
}

// ---------------- single-block exclusive scan of degrees -> offsets, cursor --
__global__ __launch_bounds__(1024) void scan_kernel(int* __restrict__ cursor,
                                                    int* __restrict__ offsets) {
    __shared__ int sums[1024];
    const int C = 49;                         // ceil(50000/1024)
    int t = threadIdx.x;
    int start = t * C;
    int end = min(start + C, N_NODES);
    int s = 0;
    for (int i = start; i < end; ++i) s += cursor[i];
    sums[t] = s;
    __syncthreads();
    for (int off = 1; off < 1024; off <<= 1) {
        int v = (t >= off) ? sums[t - off] : 0;
        __syncthreads();
        sums[t] += v;
        __syncthreads();
    }
    int run = (t == 0) ? 0 : sums[t - 1];     // exclusive prefix
    for (int i = start; i < end; ++i) {
        int d = cursor[i];
        offsets[i] = run;
        cursor[i] = run;
        run += d;
    }
    if (t == 1023) offsets[N_NODES] = run;    // = N_EDGES
}

// ---------------- scatter edges into dst-sorted order ----------------
__global__ void scatter_kernel(const int* __restrict__ src, const int* __restrict__ dst,
                               const float* __restrict__ w, int* __restrict__ cursor,
                               int* __restrict__ ssrc, float* __restrict__ sw) {
    int e = blockIdx.x * blockDim.x + threadIdx.x;
    if (e < N_EDGES) {
        int d = dst[e];
        int pos = atomicAdd(&cursor[d], 1);
        ssrc[pos] = src[e];
        sw[pos] = w[e];
    }
}

// ---------------- per-node max over incoming messages (1 wave / node) -------
__global__ __launch_bounds__(256) void neigh_max_kernel(
    const float* __restrict__ h, const int* __restrict__ offsets,
    const int* __restrict__ ssrc, const float* __restrict__ sw,
    float* __restrict__ neigh)
{
    int gwave = (blockIdx.x * 256 + threadIdx.x) >> 6;
    int lane = threadIdx.x & 63;
    if (gwave >= N_NODES) return;
    int beg = offsets[gwave], end = offsets[gwave + 1];
    float mx = -3.4e38f, my = -3.4e38f;
    for (int e = beg; e < end; ++e) {
        int s = ssrc[e];
        float w = sw[e];
        float2 v = *(const float2*)(h + (size_t)s * DF + lane * 2);
        mx = fmaxf(mx, v.x * w);
        my = fmaxf(my, v.y * w);
    }
    if (beg == end) { mx = 0.f; my = 0.f; }   // zero-degree nodes -> 0
    float2 o; o.x = mx; o.y = my;
    *(float2*)(neigh + (size_t)gwave * DF + lane * 2) = o;
}

extern "C" void kernel_launch(void* const* d_in, const int* in_sizes, int n_in,
                              void* d_out, int out_size, void* d_ws, size_t ws_size,
                              hipStream_t stream) {
    const float* feat    = (const float*)d_in[0];
    const float* weight  = (const float*)d_in[1];
    const int*   src     = (const int*)d_in[2];
    const int*   dst     = (const int*)d_in[3];
    const float* W_pool  = (const float*)d_in[4];
    const float* b_pool  = (const float*)d_in[5];
    const float* W_neigh = (const float*)d_in[6];
    const float* b_neigh = (const float*)d_in[7];
    float* out = (float*)d_out;

    char* ws = (char*)d_ws;
    float* h       = (float*)(ws);                 // 25,600,000 B
    float* Wp_t    = (float*)(ws + 25600000);      // 65,536 B
    float* Wn1_t   = (float*)(ws + 25665536);      // 65,536 B
    float* Wn2_t   = (float*)(ws + 25731072);      // 65,536 B
    int*   offsets = (int*)  (ws + 25796608);      // 200,064 B (N+1 ints, padded)
    int*   cursor  = (int*)  (ws + 25996672);      // 200,064 B
    int*   ssrc    = (int*)  (ws + 26196736);      // 2,560,000 B
    float* sw      = (float*)(ws + 28756736);      // 2,560,000 B -> 31.3 MB total

    const int TT = 3 * 128 * 128;
    setup_kernel<<<(TT + N_NODES + 255) / 256, 256, 0, stream>>>(
        W_pool, W_neigh, Wp_t, Wn1_t, Wn2_t, cursor);

    // h = feat @ W_pool.T + b_pool
    gemm_fused<<<(N_NODES + 31) / 32, 256, 0, stream>>>(
        feat, Wp_t, nullptr, nullptr, b_pool, h, 1);

    hist_kernel<<<(N_EDGES + 255) / 256, 256, 0, stream>>>(dst, cursor);
    scan_kernel<<<1, 1024, 0, stream>>>(cursor, offsets);
    scatter_kernel<<<(N_EDGES + 255) / 256, 256, 0, stream>>>(
        src, dst, weight, cursor, ssrc, sw);

    // neigh (stored in d_out) = segment_max(h[src]*w, dst), 0 for empty
    neigh_max_kernel<<<(N_NODES + 3) / 4, 256, 0, stream>>>(h, offsets, ssrc, sw, out);

    // out = feat @ Wn1.T + neigh @ Wn2.T + b_neigh   (neigh aliases out; safe)
    gemm_fused<<<(N_NODES + 31) / 32, 256, 0, stream>>>(
        feat, Wn1_t, out, Wn2_t, b_neigh, out, 2);
}

// Round 2
// 324.932 us; speedup vs baseline: 1.3413x; 1.3413x over previous
//
#include <hip/hip_runtime.h>
#include <cstdint>
#include <cstddef>

#define N_NODES 50000
#define N_EDGES 640000
#define DF 128
#define NB_SCAN 49   // ceil(50000/1024)

// ---------------- setup: transpose weights to k-major + zero cursor ----------
__global__ void setup_kernel(const float* __restrict__ W_pool,
                             const float* __restrict__ W_neigh,
                             float* __restrict__ Wp_t,
                             float* __restrict__ Wn1_t,
                             float* __restrict__ Wn2_t,
                             int* __restrict__ cursor) {
    int idx = blockIdx.x * blockDim.x + threadIdx.x;
    const int TT = 3 * 128 * 128;
    if (idx < TT) {
        int m = idx >> 14;       // which matrix
        int r = idx & 16383;
        int k = r >> 7, o = r & 127;
        if (m == 0)      Wp_t[r]  = W_pool[o * 128 + k];
        else if (m == 1) Wn1_t[r] = W_neigh[o * 256 + k];
        else             Wn2_t[r] = W_neigh[o * 256 + 128 + k];
    } else {
        int i = idx - TT;
        if (i < N_NODES) cursor[i] = 0;
    }
}

// ---------------- tiled fp32 GEMM: out[n][o] = bias[o] + sum_p A_p[n][:] @ Wt_p
// Wt is k-major: Wt[k*128 + o]. 32 rows/block, 256 threads, 4x4 micro-tile.
// NOTE: A1 may alias out (neigh lives in d_out): each block stages its own
// 32 A-rows into LDS before storing those same 32 rows -> no hazard.
__global__ __launch_bounds__(256) void gemm_fused(
    const float* __restrict__ A0, const float* __restrict__ Wt0,
    const float* A1, const float* Wt1,
    const float* __restrict__ bias, float* out, int nphase)
{
    __shared__ float Wl[64 * 128];   // k-half-major
    __shared__ float Al[32 * 128];   // row-major
    const int t = threadIdx.x;
    const int colg = t & 31;         // float4 column group: cols 4*colg..+3
    const int rowg = t >> 5;         // 0..7 -> rows rowg*4..+3
    const int r0 = blockIdx.x * 32;

    float4 acc[4];
    {
        float4 bv = ((const float4*)bias)[colg];
        #pragma unroll
        for (int ri = 0; ri < 4; ++ri) acc[ri] = bv;
    }

    for (int p = 0; p < nphase; ++p) {
        const float* A  = p ? A1  : A0;
        const float* Wt = p ? Wt1 : Wt0;

        // stage A tile: 32 rows x 128 cols = 1024 float4, 4 per thread
        {
            const float4* A4 = (const float4*)A;
            float4* Al4 = (float4*)Al;
            #pragma unroll
            for (int i = 0; i < 4; ++i) {
                int idx = i * 256 + t;
                int row = idx >> 5, c4 = idx & 31;
                float4 v = make_float4(0.f, 0.f, 0.f, 0.f);
                if (r0 + row < N_NODES) v = A4[(size_t)(r0 + row) * 32 + c4];
                Al4[idx] = v;
            }
        }

        #pragma unroll
        for (int h = 0; h < 2; ++h) {            // two 64-k halves of W
            __syncthreads();
            {
                const float4* Wt4 = (const float4*)(Wt + h * 64 * 128);
                float4* Wl4 = (float4*)Wl;
                #pragma unroll
                for (int i = 0; i < 8; ++i)
                    Wl4[i * 256 + t] = Wt4[i * 256 + t];
            }
            __syncthreads();

            for (int k = 0; k < 64; k += 4) {
                float4 b[4], a[4];
                #pragma unroll
                for (int j = 0; j < 4; ++j)
                    b[j] = ((const float4*)Wl)[(k + j) * 32 + colg];
                #pragma unroll
                for (int ri = 0; ri < 4; ++ri)
                    a[ri] = ((const float4*)Al)[(rowg * 4 + ri) * 32 + ((h * 64 + k) >> 2)];
                #pragma unroll
                for (int ri = 0; ri < 4; ++ri) {
                    float4 av = a[ri];
                    acc[ri].x = fmaf(av.x, b[0].x, fmaf(av.y, b[1].x, fmaf(av.z, b[2].x, fmaf(av.w, b[3].x, acc[ri].x))));
                    acc[ri].y = fmaf(av.x, b[0].y, fmaf(av.y, b[1].y, fmaf(av.z, b[2].y, fmaf(av.w, b[3].y, acc[ri].y))));
                    acc[ri].z = fmaf(av.x, b[0].z, fmaf(av.y, b[1].z, fmaf(av.z, b[2].z, fmaf(av.w, b[3].z, acc[ri].z))));
                    acc[ri].w = fmaf(av.x, b[0].w, fmaf(av.y, b[1].w, fmaf(av.z, b[2].w, fmaf(av.w, b[3].w, acc[ri].w))));
                }
            }
        }
        __syncthreads();   // before next phase restages Al
    }

    #pragma unroll
    for (int ri = 0; ri < 4; ++ri) {
        int row = r0 + rowg * 4 + ri;
        if (row < N_NODES) ((float4*)out)[(size_t)row * 32 + colg] = acc[ri];
    }
}

// ---------------- degree histogram ----------------
__global__ void hist_kernel(const int* __restrict__ dst, int* __restrict__ cursor) {
    int e = blockIdx.x * blockDim.x + threadIdx.x;
    if (e < N_EDGES) atomicAdd(&cursor[dst[e]], 1);
}

// ---------------- 3-stage hierarchical exclusive scan ----------------
// stage 1: per-block sums of 1024 degrees
__global__ __launch_bounds__(1024) void scan_reduce(const int* __restrict__ cursor,
                                                    int* __restrict__ blocksums) {
    __shared__ int red[1024];
    int t = threadIdx.x;
    int i = blockIdx.x * 1024 + t;
    red[t] = (i < N_NODES) ? cursor[i] : 0;
    __syncthreads();
    #pragma unroll
    for (int off = 512; off > 0; off >>= 1) {
        if (t < off) red[t] += red[t + off];
        __syncthreads();
    }
    if (t == 0) blocksums[blockIdx.x] = red[0];
}

// stage 2: one wave scans the 49 block sums -> exclusive offsets per block
__global__ void scan_tops(int* __restrict__ blocksums, int* __restrict__ offsets) {
    int t = threadIdx.x;             // 64 threads
    int orig = (t < NB_SCAN) ? blocksums[t] : 0;
    int v = orig;
    #pragma unroll
    for (int off = 1; off < 64; off <<= 1) {
        int u = __shfl_up(v, off, 64);
        if (t >= off) v += u;
    }
    if (t < NB_SCAN) blocksums[t] = v - orig;        // exclusive
    if (t == NB_SCAN - 1) offsets[N_NODES] = v;      // total = N_EDGES
}

// stage 3: block-level Hillis-Steele scan + block offset -> offsets, cursor
__global__ __launch_bounds__(1024) void scan_apply(int* __restrict__ cursor,
                                                   int* __restrict__ offsets,
                                                   const int* __restrict__ blocksums) {
    __shared__ int s[1024];
    int t = threadIdx.x;
    int i = blockIdx.x * 1024 + t;
    int v = (i < N_NODES) ? cursor[i] : 0;
    s[t] = v;
    __syncthreads();
    #pragma unroll
    for (int off = 1; off < 1024; off <<= 1) {
        int u = (t >= off) ? s[t - off] : 0;
        __syncthreads();
        s[t] += u;
        __syncthreads();
    }
    if (i < N_NODES) {
        int excl = s[t] - v + blocksums[blockIdx.x];
        offsets[i] = excl;
        cursor[i] = excl;
    }
}

// ---------------- scatter edges into dst-sorted order ----------------
__global__ void scatter_kernel(const int* __restrict__ src, const int* __restrict__ dst,
                               const float* __restrict__ w, int* __restrict__ cursor,
                               int* __restrict__ ssrc, float* __restrict__ sw) {
    int e = blockIdx.x * blockDim.x + threadIdx.x;
    if (e < N_EDGES) {
        int d = dst[e];
        int pos = atomicAdd(&cursor[d], 1);
        ssrc[pos] = src[e];
        sw[pos] = w[e];
    }
}

// ---------------- per-node max over incoming messages (1 wave / node) -------
__global__ __launch_bounds__(256) void neigh_max_kernel(
    const float* __restrict__ h, const int* __restrict__ offsets,
    const int* __restrict__ ssrc, const float* __restrict__ sw,
    float* __restrict__ neigh)
{
    int gwave = (blockIdx.x * 256 + threadIdx.x) >> 6;
    int lane = threadIdx.x & 63;
    if (gwave >= N_NODES) return;
    int beg = offsets[gwave], end = offsets[gwave + 1];
    float mx = -3.4e38f, my = -3.4e38f;
    for (int e = beg; e < end; ++e) {
        int s = ssrc[e];
        float w = sw[e];
        float2 v = *(const float2*)(h + (size_t)s * DF + lane * 2);
        mx = fmaxf(mx, v.x * w);
        my = fmaxf(my, v.y * w);
    }
    if (beg == end) { mx = 0.f; my = 0.f; }   // zero-degree nodes -> 0
    float2 o; o.x = mx; o.y = my;
    *(float2*)(neigh + (size_t)gwave * DF + lane * 2) = o;
}

extern "C" void kernel_launch(void* const* d_in, const int* in_sizes, int n_in,
                              void* d_out, int out_size, void* d_ws, size_t ws_size,
                              hipStream_t stream) {
    const float* feat    = (const float*)d_in[0];
    const float* weight  = (const float*)d_in[1];
    const int*   src     = (const int*)d_in[2];
    const int*   dst     = (const int*)d_in[3];
    const float* W_pool  = (const float*)d_in[4];
    const float* b_pool  = (const float*)d_in[5];
    const float* W_neigh = (const float*)d_in[6];
    const float* b_neigh = (const float*)d_in[7];
    float* out = (float*)d_out;

    char* ws = (char*)d_ws;
    float* h         = (float*)(ws);                 // 25,600,000 B
    float* Wp_t      = (float*)(ws + 25600000);      // 65,536 B
    float* Wn1_t     = (float*)(ws + 25665536);      // 65,536 B
    float* Wn2_t     = (float*)(ws + 25731072);      // 65,536 B
    int*   offsets   = (int*)  (ws + 25796608);      // 200,064 B (N+1 ints, padded)
    int*   cursor    = (int*)  (ws + 25996672);      // 200,064 B
    int*   ssrc      = (int*)  (ws + 26196736);      // 2,560,000 B
    float* sw        = (float*)(ws + 28756736);      // 2,560,000 B
    int*   blocksums = (int*)  (ws + 31316736);      // 256 B -> ~31.3 MB total

    const int TT = 3 * 128 * 128;
    setup_kernel<<<(TT + N_NODES + 255) / 256, 256, 0, stream>>>(
        W_pool, W_neigh, Wp_t, Wn1_t, Wn2_t, cursor);

    // h = feat @ W_pool.T + b_pool
    gemm_fused<<<(N_NODES + 31) / 32, 256, 0, stream>>>(
        feat, Wp_t, nullptr, nullptr, b_pool, h, 1);

    hist_kernel<<<(N_EDGES + 255) / 256, 256, 0, stream>>>(dst, cursor);

    scan_reduce<<<NB_SCAN, 1024, 0, stream>>>(cursor, blocksums);
    scan_tops<<<1, 64, 0, stream>>>(blocksums, offsets);
    scan_apply<<<NB_SCAN, 1024, 0, stream>>>(cursor, offsets, blocksums);

    scatter_kernel<<<(N_EDGES + 255) / 256, 256, 0, stream>>>(
        src, dst, weight, cursor, ssrc, sw);

    // neigh (stored in d_out) = segment_max(h[src]*w, dst), 0 for empty
    neigh_max_kernel<<<(N_NODES + 3) / 4, 256, 0, stream>>>(h, offsets, ssrc, sw, out);

    // out = feat @ Wn1.T + neigh @ Wn2.T + b_neigh   (neigh aliases out; safe)
    gemm_fused<<<(N_NODES + 31) / 32, 256, 0, stream>>>(
        feat, Wn1_t, out, Wn2_t, b_neigh, out, 2);
}

// Round 3
// 284.445 us; speedup vs baseline: 1.5322x; 1.1423x over previous
//
#include <hip/hip_runtime.h>
#include <cstdint>
#include <cstddef>

#define N_NODES 50000
#define N_EDGES 640000
#define DF 128
#define NB_SCAN 49   // ceil(50000/1024)

__device__ inline unsigned short f2bf(float f) {            // RNE float->bf16
    unsigned int u = __float_as_uint(f);
    return (unsigned short)((u + 0x7fffu + ((u >> 16) & 1u)) >> 16);
}

// ---------------- setup: transpose weights to k-major + zero cursor ----------
__global__ void setup_kernel(const float* __restrict__ W_pool,
                             const float* __restrict__ W_neigh,
                             float* __restrict__ Wp_t,
                             float* __restrict__ Wn1_t,
                             float* __restrict__ Wn2_t,
                             int* __restrict__ cursor) {
    int idx = blockIdx.x * blockDim.x + threadIdx.x;
    const int TT = 3 * 128 * 128;
    if (idx < TT) {
        int m = idx >> 14;       // which matrix
        int r = idx & 16383;
        int k = r >> 7, o = r & 127;
        if (m == 0)      Wp_t[r]  = W_pool[o * 128 + k];
        else if (m == 1) Wn1_t[r] = W_neigh[o * 256 + k];
        else             Wn2_t[r] = W_neigh[o * 256 + 128 + k];
    } else {
        int i = idx - TT;
        if (i < N_NODES) cursor[i] = 0;
    }
}

// ---------------- tiled fp32 GEMM: out[n][o] = bias[o] + sum_p A_p[n][:] @ Wt_p
// Wt is k-major: Wt[k*128 + o]. 32 rows/block, 256 threads, 4x4 micro-tile.
// If out_bf != nullptr, results are stored as bf16 (RNE) there instead of out.
// NOTE: A1 may alias out (neigh lives in d_out): each block stages its own
// 32 A-rows into LDS before storing those same 32 rows -> no hazard.
__global__ __launch_bounds__(256) void gemm_fused(
    const float* __restrict__ A0, const float* __restrict__ Wt0,
    const float* A1, const float* Wt1,
    const float* __restrict__ bias, float* out,
    unsigned short* out_bf, int nphase)
{
    __shared__ float Wl[64 * 128];   // k-half-major
    __shared__ float Al[32 * 128];   // row-major
    const int t = threadIdx.x;
    const int colg = t & 31;         // float4 column group: cols 4*colg..+3
    const int rowg = t >> 5;         // 0..7 -> rows rowg*4..+3
    const int r0 = blockIdx.x * 32;

    float4 acc[4];
    {
        float4 bv = ((const float4*)bias)[colg];
        #pragma unroll
        for (int ri = 0; ri < 4; ++ri) acc[ri] = bv;
    }

    for (int p = 0; p < nphase; ++p) {
        const float* A  = p ? A1  : A0;
        const float* Wt = p ? Wt1 : Wt0;

        // stage A tile: 32 rows x 128 cols = 1024 float4, 4 per thread
        {
            const float4* A4 = (const float4*)A;
            float4* Al4 = (float4*)Al;
            #pragma unroll
            for (int i = 0; i < 4; ++i) {
                int idx = i * 256 + t;
                int row = idx >> 5, c4 = idx & 31;
                float4 v = make_float4(0.f, 0.f, 0.f, 0.f);
                if (r0 + row < N_NODES) v = A4[(size_t)(r0 + row) * 32 + c4];
                Al4[idx] = v;
            }
        }

        #pragma unroll
        for (int h = 0; h < 2; ++h) {            // two 64-k halves of W
            __syncthreads();
            {
                const float4* Wt4 = (const float4*)(Wt + h * 64 * 128);
                float4* Wl4 = (float4*)Wl;
                #pragma unroll
                for (int i = 0; i < 8; ++i)
                    Wl4[i * 256 + t] = Wt4[i * 256 + t];
            }
            __syncthreads();

            for (int k = 0; k < 64; k += 4) {
                float4 b[4], a[4];
                #pragma unroll
                for (int j = 0; j < 4; ++j)
                    b[j] = ((const float4*)Wl)[(k + j) * 32 + colg];
                #pragma unroll
                for (int ri = 0; ri < 4; ++ri)
                    a[ri] = ((const float4*)Al)[(rowg * 4 + ri) * 32 + ((h * 64 + k) >> 2)];
                #pragma unroll
                for (int ri = 0; ri < 4; ++ri) {
                    float4 av = a[ri];
                    acc[ri].x = fmaf(av.x, b[0].x, fmaf(av.y, b[1].x, fmaf(av.z, b[2].x, fmaf(av.w, b[3].x, acc[ri].x))));
                    acc[ri].y = fmaf(av.x, b[0].y, fmaf(av.y, b[1].y, fmaf(av.z, b[2].y, fmaf(av.w, b[3].y, acc[ri].y))));
                    acc[ri].z = fmaf(av.x, b[0].z, fmaf(av.y, b[1].z, fmaf(av.z, b[2].z, fmaf(av.w, b[3].z, acc[ri].z))));
                    acc[ri].w = fmaf(av.x, b[0].w, fmaf(av.y, b[1].w, fmaf(av.z, b[2].w, fmaf(av.w, b[3].w, acc[ri].w))));
                }
            }
        }
        __syncthreads();   // before next phase restages Al
    }

    if (out_bf) {
        #pragma unroll
        for (int ri = 0; ri < 4; ++ri) {
            int row = r0 + rowg * 4 + ri;
            if (row < N_NODES) {
                ushort4 o;
                o.x = f2bf(acc[ri].x); o.y = f2bf(acc[ri].y);
                o.z = f2bf(acc[ri].z); o.w = f2bf(acc[ri].w);
                *(ushort4*)(out_bf + (size_t)row * DF + colg * 4) = o;
            }
        }
    } else {
        #pragma unroll
        for (int ri = 0; ri < 4; ++ri) {
            int row = r0 + rowg * 4 + ri;
            if (row < N_NODES) ((float4*)out)[(size_t)row * 32 + colg] = acc[ri];
        }
    }
}

// ---------------- degree histogram (4 edges/thread, int4) ----------------
__global__ void hist_kernel(const int4* __restrict__ dst4, int* __restrict__ cursor) {
    int i = blockIdx.x * blockDim.x + threadIdx.x;
    if (i < N_EDGES / 4) {
        int4 d = dst4[i];
        atomicAdd(&cursor[d.x], 1);
        atomicAdd(&cursor[d.y], 1);
        atomicAdd(&cursor[d.z], 1);
        atomicAdd(&cursor[d.w], 1);
    }
}

// ---------------- 3-stage hierarchical exclusive scan ----------------
__global__ __launch_bounds__(1024) void scan_reduce(const int* __restrict__ cursor,
                                                    int* __restrict__ blocksums) {
    __shared__ int red[1024];
    int t = threadIdx.x;
    int i = blockIdx.x * 1024 + t;
    red[t] = (i < N_NODES) ? cursor[i] : 0;
    __syncthreads();
    #pragma unroll
    for (int off = 512; off > 0; off >>= 1) {
        if (t < off) red[t] += red[t + off];
        __syncthreads();
    }
    if (t == 0) blocksums[blockIdx.x] = red[0];
}

__global__ void scan_tops(int* __restrict__ blocksums, int* __restrict__ offsets) {
    int t = threadIdx.x;             // 64 threads
    int orig = (t < NB_SCAN) ? blocksums[t] : 0;
    int v = orig;
    #pragma unroll
    for (int off = 1; off < 64; off <<= 1) {
        int u = __shfl_up(v, off, 64);
        if (t >= off) v += u;
    }
    if (t < NB_SCAN) blocksums[t] = v - orig;        // exclusive
    if (t == NB_SCAN - 1) offsets[N_NODES] = v;      // total = N_EDGES
}

__global__ __launch_bounds__(1024) void scan_apply(int* __restrict__ cursor,
                                                   int* __restrict__ offsets,
                                                   const int* __restrict__ blocksums) {
    __shared__ int s[1024];
    int t = threadIdx.x;
    int i = blockIdx.x * 1024 + t;
    int v = (i < N_NODES) ? cursor[i] : 0;
    s[t] = v;
    __syncthreads();
    #pragma unroll
    for (int off = 1; off < 1024; off <<= 1) {
        int u = (t >= off) ? s[t - off] : 0;
        __syncthreads();
        s[t] += u;
        __syncthreads();
    }
    if (i < N_NODES) {
        int excl = s[t] - v + blocksums[blockIdx.x];
        offsets[i] = excl;
        cursor[i] = excl;
    }
}

// ---------------- scatter edges into dst-sorted order ----------------
__global__ void scatter_kernel(const int* __restrict__ src, const int* __restrict__ dst,
                               const float* __restrict__ w, int* __restrict__ cursor,
                               int* __restrict__ ssrc, float* __restrict__ sw) {
    int e = blockIdx.x * blockDim.x + threadIdx.x;
    if (e < N_EDGES) {
        int d = dst[e];
        int pos = atomicAdd(&cursor[d], 1);
        ssrc[pos] = src[e];
        sw[pos] = w[e];
    }
}

// ---------------- per-node max over incoming messages (1 wave / node) -------
// h is bf16 (row = 256 B). Half-wave 0 gathers edge e, half-wave 1 edge e+1:
// one uint2 load/lane = 4 bf16 = cols 4q..4q+3; 2 rows per load instruction.
// 4 edges in flight per loop iteration. Edge meta via scalar loads
// (readfirstlane'd node id -> s_load), no per-edge VGPR broadcast chain.
__global__ __launch_bounds__(256) void neigh_max_kernel(
    const unsigned short* __restrict__ hb, const int* __restrict__ offsets,
    const int* __restrict__ ssrc, const float* __restrict__ sw,
    float* __restrict__ neigh)
{
    int gwave = (blockIdx.x * 256 + threadIdx.x) >> 6;
    if (gwave >= N_NODES) return;
    int node = __builtin_amdgcn_readfirstlane(gwave);
    int lane = threadIdx.x & 63;
    const int half = lane >> 5;      // 0: even edge of pair, 1: odd edge
    const int q = lane & 31;         // column quarter: cols 4q..4q+3

    int beg = offsets[node], end = offsets[node + 1];
    float4 acc = make_float4(-3.4e38f, -3.4e38f, -3.4e38f, -3.4e38f);

    for (int e = beg; e < end; e += 4) {
        int i0 = e;
        int i1 = min(e + 1, end - 1);
        int i2 = min(e + 2, end - 1);
        int i3 = min(e + 3, end - 1);
        int   s0 = ssrc[i0], s1 = ssrc[i1], s2 = ssrc[i2], s3 = ssrc[i3];
        float w0 = sw[i0],  w1 = sw[i1],  w2 = sw[i2],  w3 = sw[i3];
        int   sA = half ? s1 : s0;  float wA = half ? w1 : w0;
        int   sB = half ? s3 : s2;  float wB = half ? w3 : w2;
        uint2 pA = *(const uint2*)(hb + (size_t)sA * DF + q * 4);
        uint2 pB = *(const uint2*)(hb + (size_t)sB * DF + q * 4);
        acc.x = fmaxf(acc.x, __uint_as_float(pA.x << 16)          * wA);
        acc.y = fmaxf(acc.y, __uint_as_float(pA.x & 0xffff0000u)  * wA);
        acc.z = fmaxf(acc.z, __uint_as_float(pA.y << 16)          * wA);
        acc.w = fmaxf(acc.w, __uint_as_float(pA.y & 0xffff0000u)  * wA);
        acc.x = fmaxf(acc.x, __uint_as_float(pB.x << 16)          * wB);
        acc.y = fmaxf(acc.y, __uint_as_float(pB.x & 0xffff0000u)  * wB);
        acc.z = fmaxf(acc.z, __uint_as_float(pB.y << 16)          * wB);
        acc.w = fmaxf(acc.w, __uint_as_float(pB.y & 0xffff0000u)  * wB);
    }

    // combine the two half-wave accumulators (lane L <-> lane L^32)
    float4 o;
    o.x = fmaxf(acc.x, __shfl_xor(acc.x, 32));
    o.y = fmaxf(acc.y, __shfl_xor(acc.y, 32));
    o.z = fmaxf(acc.z, __shfl_xor(acc.z, 32));
    o.w = fmaxf(acc.w, __shfl_xor(acc.w, 32));
    if (beg == end) o = make_float4(0.f, 0.f, 0.f, 0.f);
    if (half == 0)
        ((float4*)(neigh + (size_t)node * DF))[q] = o;
}

extern "C" void kernel_launch(void* const* d_in, const int* in_sizes, int n_in,
                              void* d_out, int out_size, void* d_ws, size_t ws_size,
                              hipStream_t stream) {
    const float* feat    = (const float*)d_in[0];
    const float* weight  = (const float*)d_in[1];
    const int*   src     = (const int*)d_in[2];
    const int*   dst     = (const int*)d_in[3];
    const float* W_pool  = (const float*)d_in[4];
    const float* b_pool  = (const float*)d_in[5];
    const float* W_neigh = (const float*)d_in[6];
    const float* b_neigh = (const float*)d_in[7];
    float* out = (float*)d_out;

    char* ws = (char*)d_ws;
    unsigned short* hb   = (unsigned short*)(ws);    // 12,800,000 B
    float* Wp_t      = (float*)(ws + 12800000);      // 65,536 B
    float* Wn1_t     = (float*)(ws + 12865536);      // 65,536 B
    float* Wn2_t     = (float*)(ws + 12931072);      // 65,536 B
    int*   offsets   = (int*)  (ws + 12996608);      // 200,064 B (N+1 ints, padded)
    int*   cursor    = (int*)  (ws + 13196672);      // 200,064 B
    int*   ssrc      = (int*)  (ws + 13396736);      // 2,560,000 B
    float* sw        = (float*)(ws + 15956736);      // 2,560,000 B
    int*   blocksums = (int*)  (ws + 18516736);      // 256 B -> ~18.5 MB total

    const int TT = 3 * 128 * 128;
    setup_kernel<<<(TT + N_NODES + 255) / 256, 256, 0, stream>>>(
        W_pool, W_neigh, Wp_t, Wn1_t, Wn2_t, cursor);

    // hb = bf16(feat @ W_pool.T + b_pool)
    gemm_fused<<<(N_NODES + 31) / 32, 256, 0, stream>>>(
        feat, Wp_t, nullptr, nullptr, b_pool, nullptr, hb, 1);

    hist_kernel<<<(N_EDGES / 4 + 255) / 256, 256, 0, stream>>>((const int4*)dst, cursor);

    scan_reduce<<<NB_SCAN, 1024, 0, stream>>>(cursor, blocksums);
    scan_tops<<<1, 64, 0, stream>>>(blocksums, offsets);
    scan_apply<<<NB_SCAN, 1024, 0, stream>>>(cursor, offsets, blocksums);

    scatter_kernel<<<(N_EDGES + 255) / 256, 256, 0, stream>>>(
        src, dst, weight, cursor, ssrc, sw);

    // neigh (stored in d_out) = segment_max(h[src]*w, dst), 0 for empty
    neigh_max_kernel<<<(N_NODES + 3) / 4, 256, 0, stream>>>(hb, offsets, ssrc, sw, out);

    // out = feat @ Wn1.T + neigh @ Wn2.T + b_neigh   (neigh aliases out; safe)
    gemm_fused<<<(N_NODES + 31) / 32, 256, 0, stream>>>(
        feat, Wn1_t, out, Wn2_t, b_neigh, out, nullptr, 2);
}

// Round 4
// 233.040 us; speedup vs baseline: 1.8701x; 1.2206x over previous
//
#include <hip/hip_runtime.h>
#include <cstdint>
#include <cstddef>

#define N_NODES 50000
#define N_EDGES 640000
#define DF 128
#define NB_SCAN 49   // ceil(50000/1024)

typedef __attribute__((ext_vector_type(8))) short bf16x8;
typedef __attribute__((ext_vector_type(4))) float f32x4;

__device__ inline unsigned short f2bf(float f) {            // RNE float->bf16
    unsigned int u = __float_as_uint(f);
    return (unsigned short)((u + 0x7fffu + ((u >> 16) & 1u)) >> 16);
}

// ---------------- setup ----------------
// 1) feat fp32 -> featb bf16 (row-major), 4 elems/thread
// 2) W_pool / W_neigh[:, :128] / W_neigh[:, 128:] -> B-fragment-order bf16:
//    Wf[((c*4+t)*64 + L)*8 + j] = W[c*16+(L&15)][t*32+(L>>4)*8+j]
//    so a wave's b_frag for col-tile c, k-tile t is one 16B load per lane.
// 3) zero cursor
#define NF4 (N_NODES * DF / 4)        // 1,600,000
#define NWG (3 * 2048)                // frag groups of 8
__global__ void setup_kernel(const float* __restrict__ feat,
                             const float* __restrict__ W_pool,
                             const float* __restrict__ W_neigh,
                             unsigned short* __restrict__ featb,
                             unsigned short* __restrict__ Wp_f,
                             unsigned short* __restrict__ Wn1_f,
                             unsigned short* __restrict__ Wn2_f,
                             int* __restrict__ cursor) {
    int idx = blockIdx.x * blockDim.x + threadIdx.x;
    if (idx < NF4) {
        float4 v = ((const float4*)feat)[idx];
        ushort4 o;
        o.x = f2bf(v.x); o.y = f2bf(v.y); o.z = f2bf(v.z); o.w = f2bf(v.w);
        ((ushort4*)featb)[idx] = o;
    } else if (idx < NF4 + NWG) {
        int g = idx - NF4;
        int m = g >> 11;            // which matrix
        int r8 = g & 2047;          // (c*4+t)*64 + L
        int L = r8 & 63, t = (r8 >> 6) & 3, c = r8 >> 8;
        int o = c * 16 + (L & 15);
        int kb = t * 32 + (L >> 4) * 8;
        const float* srcp;
        unsigned short* dstp;
        if (m == 0)      { srcp = W_pool  + o * 128 + kb;       dstp = Wp_f;  }
        else if (m == 1) { srcp = W_neigh + o * 256 + kb;       dstp = Wn1_f; }
        else             { srcp = W_neigh + o * 256 + 128 + kb; dstp = Wn2_f; }
        ushort4 lo, hi;
        float4 a = ((const float4*)srcp)[0];
        float4 b = ((const float4*)srcp)[1];
        lo.x = f2bf(a.x); lo.y = f2bf(a.y); lo.z = f2bf(a.z); lo.w = f2bf(a.w);
        hi.x = f2bf(b.x); hi.y = f2bf(b.y); hi.z = f2bf(b.z); hi.w = f2bf(b.w);
        ((ushort4*)(dstp + r8 * 8))[0] = lo;
        ((ushort4*)(dstp + r8 * 8))[1] = hi;
    } else {
        int i = idx - NF4 - NWG;
        if (i < N_NODES) cursor[i] = 0;
    }
}

// ---------------- MFMA GEMM: out[n][o] = bias[o] + sum_p A_p[n][:] @ W_p^T ---
// A_p: bf16 row-major [N_NODES x 128]. B_pf: fragment-order bf16 (see setup).
// One wave = 16 rows x 128 cols = 8 accumulator tiles of 16x16, K=128/phase.
// No LDS: a_frag and b_frag are direct 16B global loads; B is L1/L2-hot.
// Output: fp32 (outf) or bf16 RNE (outb) — exactly one non-null.
__global__ __launch_bounds__(256) void gemm_mfma(
    const unsigned short* __restrict__ A0, const unsigned short* __restrict__ B0f,
    const unsigned short* A1, const unsigned short* B1f,
    const float* __restrict__ bias,
    float* __restrict__ outf, unsigned short* __restrict__ outb, int nphase)
{
    int wave = (blockIdx.x * 256 + threadIdx.x) >> 6;
    int lane = threadIdx.x & 63;
    int m0 = wave * 16;
    if (m0 >= N_NODES) return;                 // no barriers in kernel -> safe
    const int n = lane & 15, quad = lane >> 4;
    int arow = m0 + n;
    if (arow > N_NODES - 1) arow = N_NODES - 1;

    f32x4 acc[8];
    #pragma unroll
    for (int c = 0; c < 8; ++c) {
        float bv = bias[c * 16 + n];
        acc[c] = (f32x4){bv, bv, bv, bv};
    }

    for (int p = 0; p < nphase; ++p) {
        const unsigned short* A  = p ? A1  : A0;
        const unsigned short* Bf = p ? B1f : B0f;
        const unsigned short* aptr = A + (size_t)arow * DF + quad * 8;
        #pragma unroll
        for (int t = 0; t < 4; ++t) {
            bf16x8 af = *(const bf16x8*)(aptr + t * 32);
            #pragma unroll
            for (int c = 0; c < 8; ++c) {
                bf16x8 bf = *(const bf16x8*)(Bf + (size_t)((c * 4 + t) * 64 + lane) * 8);
                acc[c] = __builtin_amdgcn_mfma_f32_16x16x32_bf16(af, bf, acc[c], 0, 0, 0);
            }
        }
    }

    // D layout: lane holds D[quad*4+r][c*16+n]
    if (outf) {
        #pragma unroll
        for (int c = 0; c < 8; ++c)
            #pragma unroll
            for (int r = 0; r < 4; ++r) {
                int row = m0 + quad * 4 + r;
                if (row < N_NODES) outf[(size_t)row * DF + c * 16 + n] = acc[c][r];
            }
    } else {
        #pragma unroll
        for (int c = 0; c < 8; ++c)
            #pragma unroll
            for (int r = 0; r < 4; ++r) {
                int row = m0 + quad * 4 + r;
                if (row < N_NODES) outb[(size_t)row * DF + c * 16 + n] = f2bf(acc[c][r]);
            }
    }
}

// ---------------- degree histogram (4 edges/thread, int4) ----------------
__global__ void hist_kernel(const int4* __restrict__ dst4, int* __restrict__ cursor) {
    int i = blockIdx.x * blockDim.x + threadIdx.x;
    if (i < N_EDGES / 4) {
        int4 d = dst4[i];
        atomicAdd(&cursor[d.x], 1);
        atomicAdd(&cursor[d.y], 1);
        atomicAdd(&cursor[d.z], 1);
        atomicAdd(&cursor[d.w], 1);
    }
}

// ---------------- 3-stage hierarchical exclusive scan ----------------
__global__ __launch_bounds__(1024) void scan_reduce(const int* __restrict__ cursor,
                                                    int* __restrict__ blocksums) {
    __shared__ int red[1024];
    int t = threadIdx.x;
    int i = blockIdx.x * 1024 + t;
    red[t] = (i < N_NODES) ? cursor[i] : 0;
    __syncthreads();
    #pragma unroll
    for (int off = 512; off > 0; off >>= 1) {
        if (t < off) red[t] += red[t + off];
        __syncthreads();
    }
    if (t == 0) blocksums[blockIdx.x] = red[0];
}

__global__ void scan_tops(int* __restrict__ blocksums, int* __restrict__ offsets) {
    int t = threadIdx.x;             // 64 threads
    int orig = (t < NB_SCAN) ? blocksums[t] : 0;
    int v = orig;
    #pragma unroll
    for (int off = 1; off < 64; off <<= 1) {
        int u = __shfl_up(v, off, 64);
        if (t >= off) v += u;
    }
    if (t < NB_SCAN) blocksums[t] = v - orig;        // exclusive
    if (t == NB_SCAN - 1) offsets[N_NODES] = v;      // total = N_EDGES
}

__global__ __launch_bounds__(1024) void scan_apply(int* __restrict__ cursor,
                                                   int* __restrict__ offsets,
                                                   const int* __restrict__ blocksums) {
    __shared__ int s[1024];
    int t = threadIdx.x;
    int i = blockIdx.x * 1024 + t;
    int v = (i < N_NODES) ? cursor[i] : 0;
    s[t] = v;
    __syncthreads();
    #pragma unroll
    for (int off = 1; off < 1024; off <<= 1) {
        int u = (t >= off) ? s[t - off] : 0;
        __syncthreads();
        s[t] += u;
        __syncthreads();
    }
    if (i < N_NODES) {
        int excl = s[t] - v + blocksums[blockIdx.x];
        offsets[i] = excl;
        cursor[i] = excl;
    }
}

// ---------------- scatter edges into dst-sorted order ----------------
__global__ void scatter_kernel(const int* __restrict__ src, const int* __restrict__ dst,
                               const float* __restrict__ w, int* __restrict__ cursor,
                               int* __restrict__ ssrc, float* __restrict__ sw) {
    int e = blockIdx.x * blockDim.x + threadIdx.x;
    if (e < N_EDGES) {
        int d = dst[e];
        int pos = atomicAdd(&cursor[d], 1);
        ssrc[pos] = src[e];
        sw[pos] = w[e];
    }
}

// ---------------- per-node max over incoming messages (1 wave / node) -------
// hb bf16 (row = 256 B). Half-wave gathers even/odd edge of a pair; 8 edges
// per iteration -> 4 independent uint2 gathers in flight. Output bf16.
__global__ __launch_bounds__(256) void neigh_max_kernel(
    const unsigned short* __restrict__ hb, const int* __restrict__ offsets,
    const int* __restrict__ ssrc, const float* __restrict__ sw,
    unsigned short* __restrict__ neighb)
{
    int gwave = (blockIdx.x * 256 + threadIdx.x) >> 6;
    if (gwave >= N_NODES) return;
    int node = __builtin_amdgcn_readfirstlane(gwave);
    int lane = threadIdx.x & 63;
    const int half = lane >> 5;      // 0: even edge of pair, 1: odd edge
    const int q = lane & 31;         // column quarter: cols 4q..4q+3

    int beg = offsets[node], end = offsets[node + 1];
    float4 acc = make_float4(-3.4e38f, -3.4e38f, -3.4e38f, -3.4e38f);

    for (int e = beg; e < end; e += 8) {
        int i0 = e;
        int i1 = min(e + 1, end - 1);
        int i2 = min(e + 2, end - 1);
        int i3 = min(e + 3, end - 1);
        int i4 = min(e + 4, end - 1);
        int i5 = min(e + 5, end - 1);
        int i6 = min(e + 6, end - 1);
        int i7 = min(e + 7, end - 1);
        int   sA = half ? ssrc[i1] : ssrc[i0];  float wA = half ? sw[i1] : sw[i0];
        int   sB = half ? ssrc[i3] : ssrc[i2];  float wB = half ? sw[i3] : sw[i2];
        int   sC = half ? ssrc[i5] : ssrc[i4];  float wC = half ? sw[i5] : sw[i4];
        int   sD = half ? ssrc[i7] : ssrc[i6];  float wD = half ? sw[i7] : sw[i6];
        uint2 pA = *(const uint2*)(hb + (size_t)sA * DF + q * 4);
        uint2 pB = *(const uint2*)(hb + (size_t)sB * DF + q * 4);
        uint2 pC = *(const uint2*)(hb + (size_t)sC * DF + q * 4);
        uint2 pD = *(const uint2*)(hb + (size_t)sD * DF + q * 4);
        acc.x = fmaxf(acc.x, __uint_as_float(pA.x << 16)          * wA);
        acc.y = fmaxf(acc.y, __uint_as_float(pA.x & 0xffff0000u)  * wA);
        acc.z = fmaxf(acc.z, __uint_as_float(pA.y << 16)          * wA);
        acc.w = fmaxf(acc.w, __uint_as_float(pA.y & 0xffff0000u)  * wA);
        acc.x = fmaxf(acc.x, __uint_as_float(pB.x << 16)          * wB);
        acc.y = fmaxf(acc.y, __uint_as_float(pB.x & 0xffff0000u)  * wB);
        acc.z = fmaxf(acc.z, __uint_as_float(pB.y << 16)          * wB);
        acc.w = fmaxf(acc.w, __uint_as_float(pB.y & 0xffff0000u)  * wB);
        acc.x = fmaxf(acc.x, __uint_as_float(pC.x << 16)          * wC);
        acc.y = fmaxf(acc.y, __uint_as_float(pC.x & 0xffff0000u)  * wC);
        acc.z = fmaxf(acc.z, __uint_as_float(pC.y << 16)          * wC);
        acc.w = fmaxf(acc.w, __uint_as_float(pC.y & 0xffff0000u)  * wC);
        acc.x = fmaxf(acc.x, __uint_as_float(pD.x << 16)          * wD);
        acc.y = fmaxf(acc.y, __uint_as_float(pD.x & 0xffff0000u)  * wD);
        acc.z = fmaxf(acc.z, __uint_as_float(pD.y << 16)          * wD);
        acc.w = fmaxf(acc.w, __uint_as_float(pD.y & 0xffff0000u)  * wD);
    }

    float4 o;
    o.x = fmaxf(acc.x, __shfl_xor(acc.x, 32));
    o.y = fmaxf(acc.y, __shfl_xor(acc.y, 32));
    o.z = fmaxf(acc.z, __shfl_xor(acc.z, 32));
    o.w = fmaxf(acc.w, __shfl_xor(acc.w, 32));
    if (beg == end) o = make_float4(0.f, 0.f, 0.f, 0.f);
    if (half == 0) {
        ushort4 ob;
        ob.x = f2bf(o.x); ob.y = f2bf(o.y); ob.z = f2bf(o.z); ob.w = f2bf(o.w);
        *(ushort4*)(neighb + (size_t)node * DF + q * 4) = ob;
    }
}

extern "C" void kernel_launch(void* const* d_in, const int* in_sizes, int n_in,
                              void* d_out, int out_size, void* d_ws, size_t ws_size,
                              hipStream_t stream) {
    const float* feat    = (const float*)d_in[0];
    const float* weight  = (const float*)d_in[1];
    const int*   src     = (const int*)d_in[2];
    const int*   dst     = (const int*)d_in[3];
    const float* W_pool  = (const float*)d_in[4];
    const float* b_pool  = (const float*)d_in[5];
    const float* W_neigh = (const float*)d_in[6];
    const float* b_neigh = (const float*)d_in[7];
    float* out = (float*)d_out;

    char* ws = (char*)d_ws;
    unsigned short* featb  = (unsigned short*)(ws);              // 12,800,000 B
    unsigned short* hb     = (unsigned short*)(ws + 12800000);   // 12,800,000 B
    unsigned short* neighb = (unsigned short*)(ws + 25600000);   // 12,800,000 B
    unsigned short* Wp_f   = (unsigned short*)(ws + 38400000);   // 32,768 B
    unsigned short* Wn1_f  = (unsigned short*)(ws + 38432768);   // 32,768 B
    unsigned short* Wn2_f  = (unsigned short*)(ws + 38465536);   // 32,768 B
    int*   offsets   = (int*)  (ws + 38498304);                  // 200,064 B
    int*   cursor    = (int*)  (ws + 38698368);                  // 200,064 B
    int*   ssrc      = (int*)  (ws + 38898432);                  // 2,560,000 B
    float* sw        = (float*)(ws + 41458432);                  // 2,560,000 B
    int*   blocksums = (int*)  (ws + 44018432);                  // 256 B -> ~44 MB

    const int NSETUP = NF4 + NWG + N_NODES;
    setup_kernel<<<(NSETUP + 255) / 256, 256, 0, stream>>>(
        feat, W_pool, W_neigh, featb, Wp_f, Wn1_f, Wn2_f, cursor);

    const int GEMM_BLOCKS = ((N_NODES + 15) / 16 + 3) / 4;   // 4 waves/block

    // hb = bf16(featb @ Wp^T + b_pool)
    gemm_mfma<<<GEMM_BLOCKS, 256, 0, stream>>>(
        featb, Wp_f, nullptr, nullptr, b_pool, nullptr, hb, 1);

    hist_kernel<<<(N_EDGES / 4 + 255) / 256, 256, 0, stream>>>((const int4*)dst, cursor);

    scan_reduce<<<NB_SCAN, 1024, 0, stream>>>(cursor, blocksums);
    scan_tops<<<1, 64, 0, stream>>>(blocksums, offsets);
    scan_apply<<<NB_SCAN, 1024, 0, stream>>>(cursor, offsets, blocksums);

    scatter_kernel<<<(N_EDGES + 255) / 256, 256, 0, stream>>>(
        src, dst, weight, cursor, ssrc, sw);

    // neighb = bf16(segment_max(hb[src]*w, dst)), 0 for empty
    neigh_max_kernel<<<(N_NODES + 3) / 4, 256, 0, stream>>>(hb, offsets, ssrc, sw, neighb);

    // out = featb @ Wn1^T + neighb @ Wn2^T + b_neigh  (fp32 out)
    gemm_mfma<<<GEMM_BLOCKS, 256, 0, stream>>>(
        featb, Wn1_f, neighb, Wn2_f, b_neigh, out, nullptr, 2);
}

// Round 5
// 220.919 us; speedup vs baseline: 1.9727x; 1.0549x over previous
//
#include <hip/hip_runtime.h>
#include <cstdint>
#include <cstddef>

#define N_NODES 50000
#define N_EDGES 640000
#define DF 128
#define NB_SCAN 49   // ceil(50000/1024)

typedef __attribute__((ext_vector_type(8))) short bf16x8;
typedef __attribute__((ext_vector_type(4))) float f32x4;

__device__ inline unsigned short f2bf(float f) {            // RNE float->bf16
    unsigned int u = __float_as_uint(f);
    return (unsigned short)((u + 0x7fffu + ((u >> 16) & 1u)) >> 16);
}

// ---------------- setup ----------------
// 1) feat fp32 -> featb bf16 (row-major), 4 elems/thread
// 2) W_pool / W_neigh[:, :128] / W_neigh[:, 128:] -> B-fragment-order bf16:
//    Wf[((c*4+t)*64 + L)*8 + j] = W[c*16+(L&15)][t*32+(L>>4)*8+j]
// 3) zero cursor
#define NF4 (N_NODES * DF / 4)        // 1,600,000
#define NWG (3 * 2048)                // frag groups of 8
__global__ void setup_kernel(const float* __restrict__ feat,
                             const float* __restrict__ W_pool,
                             const float* __restrict__ W_neigh,
                             unsigned short* __restrict__ featb,
                             unsigned short* __restrict__ Wp_f,
                             unsigned short* __restrict__ Wn1_f,
                             unsigned short* __restrict__ Wn2_f,
                             int* __restrict__ cursor) {
    int idx = blockIdx.x * blockDim.x + threadIdx.x;
    if (idx < NF4) {
        float4 v = ((const float4*)feat)[idx];
        ushort4 o;
        o.x = f2bf(v.x); o.y = f2bf(v.y); o.z = f2bf(v.z); o.w = f2bf(v.w);
        ((ushort4*)featb)[idx] = o;
    } else if (idx < NF4 + NWG) {
        int g = idx - NF4;
        int m = g >> 11;            // which matrix
        int r8 = g & 2047;          // (c*4+t)*64 + L
        int L = r8 & 63, t = (r8 >> 6) & 3, c = r8 >> 8;
        int o = c * 16 + (L & 15);
        int kb = t * 32 + (L >> 4) * 8;
        const float* srcp;
        unsigned short* dstp;
        if (m == 0)      { srcp = W_pool  + o * 128 + kb;       dstp = Wp_f;  }
        else if (m == 1) { srcp = W_neigh + o * 256 + kb;       dstp = Wn1_f; }
        else             { srcp = W_neigh + o * 256 + 128 + kb; dstp = Wn2_f; }
        ushort4 lo, hi;
        float4 a = ((const float4*)srcp)[0];
        float4 b = ((const float4*)srcp)[1];
        lo.x = f2bf(a.x); lo.y = f2bf(a.y); lo.z = f2bf(a.z); lo.w = f2bf(a.w);
        hi.x = f2bf(b.x); hi.y = f2bf(b.y); hi.z = f2bf(b.z); hi.w = f2bf(b.w);
        ((ushort4*)(dstp + r8 * 8))[0] = lo;
        ((ushort4*)(dstp + r8 * 8))[1] = hi;
    } else {
        int i = idx - NF4 - NWG;
        if (i < N_NODES) cursor[i] = 0;
    }
}

// ---------------- MFMA GEMM: out[n][o] = bias[o] + sum_p A_p[n][:] @ W_p^T ---
// One wave = 16 rows x 128 cols = 8 accumulator tiles of 16x16, K=128/phase.
// No LDS: a_frag and b_frag are direct 16B global loads; B is L1/L2-hot.
__global__ __launch_bounds__(256) void gemm_mfma(
    const unsigned short* __restrict__ A0, const unsigned short* __restrict__ B0f,
    const unsigned short* A1, const unsigned short* B1f,
    const float* __restrict__ bias,
    float* __restrict__ outf, unsigned short* __restrict__ outb, int nphase)
{
    int wave = (blockIdx.x * 256 + threadIdx.x) >> 6;
    int lane = threadIdx.x & 63;
    int m0 = wave * 16;
    if (m0 >= N_NODES) return;                 // no barriers in kernel -> safe
    const int n = lane & 15, quad = lane >> 4;
    int arow = m0 + n;
    if (arow > N_NODES - 1) arow = N_NODES - 1;

    f32x4 acc[8];
    #pragma unroll
    for (int c = 0; c < 8; ++c) {
        float bv = bias[c * 16 + n];
        acc[c] = (f32x4){bv, bv, bv, bv};
    }

    for (int p = 0; p < nphase; ++p) {
        const unsigned short* A  = p ? A1  : A0;
        const unsigned short* Bf = p ? B1f : B0f;
        const unsigned short* aptr = A + (size_t)arow * DF + quad * 8;
        #pragma unroll
        for (int t = 0; t < 4; ++t) {
            bf16x8 af = *(const bf16x8*)(aptr + t * 32);
            #pragma unroll
            for (int c = 0; c < 8; ++c) {
                bf16x8 bf = *(const bf16x8*)(Bf + (size_t)((c * 4 + t) * 64 + lane) * 8);
                acc[c] = __builtin_amdgcn_mfma_f32_16x16x32_bf16(af, bf, acc[c], 0, 0, 0);
            }
        }
    }

    // D layout: lane holds D[quad*4+r][c*16+n]
    if (outf) {
        #pragma unroll
        for (int c = 0; c < 8; ++c)
            #pragma unroll
            for (int r = 0; r < 4; ++r) {
                int row = m0 + quad * 4 + r;
                if (row < N_NODES) outf[(size_t)row * DF + c * 16 + n] = acc[c][r];
            }
    } else {
        #pragma unroll
        for (int c = 0; c < 8; ++c)
            #pragma unroll
            for (int r = 0; r < 4; ++r) {
                int row = m0 + quad * 4 + r;
                if (row < N_NODES) outb[(size_t)row * DF + c * 16 + n] = f2bf(acc[c][r]);
            }
    }
}

// ---------------- degree histogram (4 edges/thread, int4) ----------------
__global__ void hist_kernel(const int4* __restrict__ dst4, int* __restrict__ cursor) {
    int i = blockIdx.x * blockDim.x + threadIdx.x;
    if (i < N_EDGES / 4) {
        int4 d = dst4[i];
        atomicAdd(&cursor[d.x], 1);
        atomicAdd(&cursor[d.y], 1);
        atomicAdd(&cursor[d.z], 1);
        atomicAdd(&cursor[d.w], 1);
    }
}

// ---------------- 3-stage hierarchical exclusive scan ----------------
__global__ __launch_bounds__(1024) void scan_reduce(const int* __restrict__ cursor,
                                                    int* __restrict__ blocksums) {
    __shared__ int red[1024];
    int t = threadIdx.x;
    int i = blockIdx.x * 1024 + t;
    red[t] = (i < N_NODES) ? cursor[i] : 0;
    __syncthreads();
    #pragma unroll
    for (int off = 512; off > 0; off >>= 1) {
        if (t < off) red[t] += red[t + off];
        __syncthreads();
    }
    if (t == 0) blocksums[blockIdx.x] = red[0];
}

__global__ void scan_tops(int* __restrict__ blocksums, int* __restrict__ offsets) {
    int t = threadIdx.x;             // 64 threads
    int orig = (t < NB_SCAN) ? blocksums[t] : 0;
    int v = orig;
    #pragma unroll
    for (int off = 1; off < 64; off <<= 1) {
        int u = __shfl_up(v, off, 64);
        if (t >= off) v += u;
    }
    if (t < NB_SCAN) blocksums[t] = v - orig;        // exclusive
    if (t == NB_SCAN - 1) offsets[N_NODES] = v;      // total = N_EDGES
}

__global__ __launch_bounds__(1024) void scan_apply(int* __restrict__ cursor,
                                                   int* __restrict__ offsets,
                                                   const int* __restrict__ blocksums) {
    __shared__ int s[1024];
    int t = threadIdx.x;
    int i = blockIdx.x * 1024 + t;
    int v = (i < N_NODES) ? cursor[i] : 0;
    s[t] = v;
    __syncthreads();
    #pragma unroll
    for (int off = 1; off < 1024; off <<= 1) {
        int u = (t >= off) ? s[t - off] : 0;
        __syncthreads();
        s[t] += u;
        __syncthreads();
    }
    if (i < N_NODES) {
        int excl = s[t] - v + blocksums[blockIdx.x];
        offsets[i] = excl;
        cursor[i] = excl;
    }
}

// ---------------- scatter edges into dst-sorted order (packed 8B) ----------
// One uint2{src, w-bits} store per edge: halves scattered-store events vs
// two 4B stores to separate arrays (cross-XCD line-transfer bound).
__global__ void scatter_kernel(const int* __restrict__ src, const int* __restrict__ dst,
                               const float* __restrict__ w, int* __restrict__ cursor,
                               uint2* __restrict__ edges) {
    int e = blockIdx.x * blockDim.x + threadIdx.x;
    if (e < N_EDGES) {
        int d = dst[e];
        int pos = atomicAdd(&cursor[d], 1);
        uint2 pk;
        pk.x = (unsigned int)src[e];
        pk.y = __float_as_uint(w[e]);
        edges[pos] = pk;
    }
}

// ---------------- per-node max over incoming messages (1 wave / node) -------
// hb bf16 (row = 256 B). Half-wave gathers even/odd edge of a pair; 8 edges
// per iteration -> 4 independent uint2 gathers in flight. Output bf16.
__global__ __launch_bounds__(256) void neigh_max_kernel(
    const unsigned short* __restrict__ hb, const int* __restrict__ offsets,
    const uint2* __restrict__ edges,
    unsigned short* __restrict__ neighb)
{
    int gwave = (blockIdx.x * 256 + threadIdx.x) >> 6;
    if (gwave >= N_NODES) return;
    int node = __builtin_amdgcn_readfirstlane(gwave);
    int lane = threadIdx.x & 63;
    const int half = lane >> 5;      // 0: even edge of pair, 1: odd edge
    const int q = lane & 31;         // column quarter: cols 4q..4q+3

    int beg = offsets[node], end = offsets[node + 1];
    float4 acc = make_float4(-3.4e38f, -3.4e38f, -3.4e38f, -3.4e38f);

    for (int e = beg; e < end; e += 8) {
        int i0 = e;
        int i1 = min(e + 1, end - 1);
        int i2 = min(e + 2, end - 1);
        int i3 = min(e + 3, end - 1);
        int i4 = min(e + 4, end - 1);
        int i5 = min(e + 5, end - 1);
        int i6 = min(e + 6, end - 1);
        int i7 = min(e + 7, end - 1);
        uint2 e0 = edges[i0], e1 = edges[i1], e2 = edges[i2], e3 = edges[i3];
        uint2 e4 = edges[i4], e5 = edges[i5], e6 = edges[i6], e7 = edges[i7];
        uint2 mA = half ? e1 : e0;
        uint2 mB = half ? e3 : e2;
        uint2 mC = half ? e5 : e4;
        uint2 mD = half ? e7 : e6;
        float wA = __uint_as_float(mA.y);
        float wB = __uint_as_float(mB.y);
        float wC = __uint_as_float(mC.y);
        float wD = __uint_as_float(mD.y);
        uint2 pA = *(const uint2*)(hb + (size_t)mA.x * DF + q * 4);
        uint2 pB = *(const uint2*)(hb + (size_t)mB.x * DF + q * 4);
        uint2 pC = *(const uint2*)(hb + (size_t)mC.x * DF + q * 4);
        uint2 pD = *(const uint2*)(hb + (size_t)mD.x * DF + q * 4);
        acc.x = fmaxf(acc.x, __uint_as_float(pA.x << 16)          * wA);
        acc.y = fmaxf(acc.y, __uint_as_float(pA.x & 0xffff0000u)  * wA);
        acc.z = fmaxf(acc.z, __uint_as_float(pA.y << 16)          * wA);
        acc.w = fmaxf(acc.w, __uint_as_float(pA.y & 0xffff0000u)  * wA);
        acc.x = fmaxf(acc.x, __uint_as_float(pB.x << 16)          * wB);
        acc.y = fmaxf(acc.y, __uint_as_float(pB.x & 0xffff0000u)  * wB);
        acc.z = fmaxf(acc.z, __uint_as_float(pB.y << 16)          * wB);
        acc.w = fmaxf(acc.w, __uint_as_float(pB.y & 0xffff0000u)  * wB);
        acc.x = fmaxf(acc.x, __uint_as_float(pC.x << 16)          * wC);
        acc.y = fmaxf(acc.y, __uint_as_float(pC.x & 0xffff0000u)  * wC);
        acc.z = fmaxf(acc.z, __uint_as_float(pC.y << 16)          * wC);
        acc.w = fmaxf(acc.w, __uint_as_float(pC.y & 0xffff0000u)  * wC);
        acc.x = fmaxf(acc.x, __uint_as_float(pD.x << 16)          * wD);
        acc.y = fmaxf(acc.y, __uint_as_float(pD.x & 0xffff0000u)  * wD);
        acc.z = fmaxf(acc.z, __uint_as_float(pD.y << 16)          * wD);
        acc.w = fmaxf(acc.w, __uint_as_float(pD.y & 0xffff0000u)  * wD);
    }

    float4 o;
    o.x = fmaxf(acc.x, __shfl_xor(acc.x, 32));
    o.y = fmaxf(acc.y, __shfl_xor(acc.y, 32));
    o.z = fmaxf(acc.z, __shfl_xor(acc.z, 32));
    o.w = fmaxf(acc.w, __shfl_xor(acc.w, 32));
    if (beg == end) o = make_float4(0.f, 0.f, 0.f, 0.f);
    if (half == 0) {
        ushort4 ob;
        ob.x = f2bf(o.x); ob.y = f2bf(o.y); ob.z = f2bf(o.z); ob.w = f2bf(o.w);
        *(ushort4*)(neighb + (size_t)node * DF + q * 4) = ob;
    }
}

extern "C" void kernel_launch(void* const* d_in, const int* in_sizes, int n_in,
                              void* d_out, int out_size, void* d_ws, size_t ws_size,
                              hipStream_t stream) {
    const float* feat    = (const float*)d_in[0];
    const float* weight  = (const float*)d_in[1];
    const int*   src     = (const int*)d_in[2];
    const int*   dst     = (const int*)d_in[3];
    const float* W_pool  = (const float*)d_in[4];
    const float* b_pool  = (const float*)d_in[5];
    const float* W_neigh = (const float*)d_in[6];
    const float* b_neigh = (const float*)d_in[7];
    float* out = (float*)d_out;

    char* ws = (char*)d_ws;
    unsigned short* featb  = (unsigned short*)(ws);              // 12,800,000 B
    unsigned short* hb     = (unsigned short*)(ws + 12800000);   // 12,800,000 B
    unsigned short* neighb = (unsigned short*)(ws + 25600000);   // 12,800,000 B
    unsigned short* Wp_f   = (unsigned short*)(ws + 38400000);   // 32,768 B
    unsigned short* Wn1_f  = (unsigned short*)(ws + 38432768);   // 32,768 B
    unsigned short* Wn2_f  = (unsigned short*)(ws + 38465536);   // 32,768 B
    int*   offsets   = (int*)  (ws + 38498304);                  // 200,064 B
    int*   cursor    = (int*)  (ws + 38698368);                  // 200,064 B
    uint2* edges     = (uint2*)(ws + 38898432);                  // 5,120,000 B
    int*   blocksums = (int*)  (ws + 44018432);                  // 256 B -> ~44 MB

    const int NSETUP = NF4 + NWG + N_NODES;
    setup_kernel<<<(NSETUP + 255) / 256, 256, 0, stream>>>(
        feat, W_pool, W_neigh, featb, Wp_f, Wn1_f, Wn2_f, cursor);

    const int GEMM_BLOCKS = ((N_NODES + 15) / 16 + 3) / 4;   // 4 waves/block

    // hb = bf16(featb @ Wp^T + b_pool)
    gemm_mfma<<<GEMM_BLOCKS, 256, 0, stream>>>(
        featb, Wp_f, nullptr, nullptr, b_pool, nullptr, hb, 1);

    hist_kernel<<<(N_EDGES / 4 + 255) / 256, 256, 0, stream>>>((const int4*)dst, cursor);

    scan_reduce<<<NB_SCAN, 1024, 0, stream>>>(cursor, blocksums);
    scan_tops<<<1, 64, 0, stream>>>(blocksums, offsets);
    scan_apply<<<NB_SCAN, 1024, 0, stream>>>(cursor, offsets, blocksums);

    scatter_kernel<<<(N_EDGES + 255) / 256, 256, 0, stream>>>(
        src, dst, weight, cursor, edges);

    // neighb = bf16(segment_max(hb[src]*w, dst)), 0 for empty
    neigh_max_kernel<<<(N_NODES + 3) / 4, 256, 0, stream>>>(hb, offsets, edges, neighb);

    // out = featb @ Wn1^T + neighb @ Wn2^T + b_neigh  (fp32 out)
    gemm_mfma<<<GEMM_BLOCKS, 256, 0, stream>>>(
        featb, Wn1_f, neighb, Wn2_f, b_neigh, out, nullptr, 2);
}